// Round 1
// baseline (473.775 us; speedup 1.0000x reference)
//
#include <hip/hip_runtime.h>

#define OUTS 7
#define NORI 8
#define NCH  256
#define FH   128
#define FW   128

// ---------------- transpose [N,C,H,W] -> [N,H,W,C] ----------------
__global__ __launch_bounds__(256) void transpose_nchw_nhwc(
    const float* __restrict__ in, float* __restrict__ out) {
  __shared__ float tile[64][65];
  const int HW = FH * FW;
  const int b  = blockIdx.z;
  const int p0 = blockIdx.x * 64;   // spatial tile base
  const int c0 = blockIdx.y * 64;   // channel tile base
  const int tx = threadIdx.x & 63;
  const int ty = threadIdx.x >> 6;  // 0..3

  const float* src = in + ((size_t)b * NCH + c0) * HW + p0;
#pragma unroll
  for (int i = 0; i < 16; ++i) {
    int c = ty + i * 4;
    tile[c][tx] = src[(size_t)c * HW + tx];   // coalesced along spatial
  }
  __syncthreads();
  float* dst = out + ((size_t)b * HW + p0) * NCH + c0;
#pragma unroll
  for (int i = 0; i < 16; ++i) {
    int p = ty + i * 4;
    dst[(size_t)p * NCH + tx] = tile[tx][p];  // coalesced along channel
  }
}

// ---------------- main RiRoIAlign kernel ----------------
// CL = channels-last feature layout ([N,H,W,C]); else original [N,C,H,W].
template <bool CL>
__global__ __launch_bounds__(256) void riroi_kernel(
    const float* __restrict__ feat, const float* __restrict__ rois,
    float* __restrict__ out) {
  const int r = blockIdx.x;
  const int c = threadIdx.x;  // channel, 0..255

  const float* roi = rois + (size_t)r * 6;
  const int   b     = (int)roi[0];
  const float cx    = roi[1] * 0.25f;
  const float cy    = roi[2] * 0.25f;
  const float rw    = fmaxf(roi[3] * 0.25f, 1.0f);
  const float rh    = fmaxf(roi[4] * 0.25f, 1.0f);
  const float theta = roi[5];

  const float bin_w = rw * (1.0f / OUTS);
  const float bin_h = rh * (1.0f / OUTS);
  const float ct = cosf(theta), st = sinf(theta);

  // sample p in [0,14): coord = -r/2 + (0.5p+0.25)*bin
  const float hbw = 0.5f * bin_w, hbh = 0.5f * bin_h;
  const float xoff = 0.25f * bin_w - 0.5f * rw;
  const float yoff = 0.25f * bin_h - 0.5f * rh;

  float acc[OUTS * OUTS];
#pragma unroll
  for (int i = 0; i < OUTS * OUTS; ++i) acc[i] = 0.f;

  const float* fb_cl = feat + (size_t)b * (FH * FW * NCH);          // CL base
  const float* fb_cf = feat + ((size_t)b * NCH + c) * (FH * FW);    // NCHW base

#pragma unroll
  for (int py = 0; py < 2 * OUTS; ++py) {
    const float yy = (float)py * hbh + yoff;
    const float yyst = yy * st, yyct = yy * ct;
#pragma unroll
    for (int px = 0; px < 2 * OUTS; ++px) {
      const float xx = (float)px * hbw + xoff;
      const float x = xx * ct + yyst + cx;
      const float y = yyct - xx * st + cy;
      if (x > -1.0f && x < (float)FW && y > -1.0f && y < (float)FH) {
        float xc = fmaxf(x, 0.f);
        float yc = fmaxf(y, 0.f);
        int x0 = (int)xc;   // floor (nonneg)
        int y0 = (int)yc;
        int x1, y1;
        float lx, ly;
        if (x0 >= FW - 1) { x0 = FW - 1; x1 = FW - 1; lx = 0.f; }
        else              { x1 = x0 + 1; lx = xc - (float)x0; }
        if (y0 >= FH - 1) { y0 = FH - 1; y1 = FH - 1; ly = 0.f; }
        else              { y1 = y0 + 1; ly = yc - (float)y0; }
        const float wx0 = 1.f - lx, wy0 = 1.f - ly;
        const float w00 = wy0 * wx0, w01 = wy0 * lx;
        const float w10 = ly * wx0,  w11 = ly * lx;
        float t00, t01, t10, t11;
        if (CL) {
          const float* r0 = fb_cl + (size_t)(y0 * FW) * NCH;
          const float* r1 = fb_cl + (size_t)(y1 * FW) * NCH;
          t00 = r0[(size_t)x0 * NCH + c];
          t01 = r0[(size_t)x1 * NCH + c];
          t10 = r1[(size_t)x0 * NCH + c];
          t11 = r1[(size_t)x1 * NCH + c];
        } else {
          t00 = fb_cf[y0 * FW + x0];
          t01 = fb_cf[y0 * FW + x1];
          t10 = fb_cf[y1 * FW + x0];
          t11 = fb_cf[y1 * FW + x1];
        }
        acc[(py >> 1) * OUTS + (px >> 1)] +=
            w00 * t00 + w01 * t01 + w10 * t10 + w11 * t11;
      }
    }
  }

  // mean over 2x2 samples
#pragma unroll
  for (int i = 0; i < OUTS * OUTS; ++i) acc[i] *= 0.25f;

  // orientation circular mix (within a group of 8 channels = within a wave)
  const float indf = (theta * 8.0f) / 6.2831853071795862f;
  const float ind0 = floorf(indf);
  const float l    = indf - ind0;
  const int   ind  = ((int)ind0) % NORI;  // ind0 >= 0
  const int   o    = c & 7;
  const int   lane = c & 63;
  const int srcLane  = (lane & 56) | ((o - ind + 8) & 7);
  const int srcLane2 = (lane & 56) | ((o - ind + 9) & 7);

  float* op = out + ((size_t)r * NCH + c) * (OUTS * OUTS);
#pragma unroll
  for (int i = 0; i < OUTS * OUTS; ++i) {
    const float v  = acc[i];
    const float vs = __shfl(v, srcLane, 64);
    const float vp = __shfl(v, srcLane2, 64);
    op[i] = (1.f - l) * vs + l * vp;
  }
}

extern "C" void kernel_launch(void* const* d_in, const int* in_sizes, int n_in,
                              void* d_out, int out_size, void* d_ws, size_t ws_size,
                              hipStream_t stream) {
  const float* feat = (const float*)d_in[0];
  const float* rois = (const float*)d_in[1];
  float* out = (float*)d_out;
  const int R = in_sizes[1] / 6;
  const int N = in_sizes[0] / (NCH * FH * FW);

  const size_t need = (size_t)N * FH * FW * NCH * sizeof(float);
  if (ws_size >= need) {
    float* ft = (float*)d_ws;
    dim3 g(FH * FW / 64, NCH / 64, N);
    transpose_nchw_nhwc<<<g, 256, 0, stream>>>(feat, ft);
    riroi_kernel<true><<<R, 256, 0, stream>>>(ft, rois, out);
  } else {
    riroi_kernel<false><<<R, 256, 0, stream>>>(feat, rois, out);
  }
}

// Round 2
// 334.333 us; speedup vs baseline: 1.4171x; 1.4171x over previous
//
#include <hip/hip_runtime.h>

#define OUTS 7
#define NORI 8
#define NCH  256
#define FH   128
#define FW   128
#define NSAMP (2 * OUTS * 2 * OUTS)  // 196

// ---------------- transpose [N,C,H,W] -> [N,H,W,C] ----------------
__global__ __launch_bounds__(256) void transpose_nchw_nhwc(
    const float* __restrict__ in, float* __restrict__ out) {
  __shared__ float tile[64][65];
  const int HW = FH * FW;
  const int b  = blockIdx.z;
  const int p0 = blockIdx.x * 64;   // spatial tile base
  const int c0 = blockIdx.y * 64;   // channel tile base
  const int tx = threadIdx.x & 63;
  const int ty = threadIdx.x >> 6;  // 0..3

  const float* src = in + ((size_t)b * NCH + c0) * HW + p0;
#pragma unroll
  for (int i = 0; i < 16; ++i) {
    int c = ty + i * 4;
    tile[c][tx] = src[(size_t)c * HW + tx];   // coalesced along spatial
  }
  __syncthreads();
  float* dst = out + ((size_t)b * HW + p0) * NCH + c0;
#pragma unroll
  for (int i = 0; i < 16; ++i) {
    int p = ty + i * 4;
    dst[(size_t)p * NCH + tx] = tile[tx][p];  // coalesced along channel
  }
}

// ---------------- main RiRoIAlign kernel ----------------
// CL: feature layout [N,H,W,C]; else [N,C,H,W].
// Phase 1: 196 threads each compute one sample's 4 gather offsets + weights -> LDS.
// Phase 2: all 256 threads (lane=channel) loop samples; broadcast LDS reads.
template <bool CL>
__global__ __launch_bounds__(256) void riroi_kernel(
    const float* __restrict__ feat, const float* __restrict__ rois,
    float* __restrict__ out) {
  __shared__ int4   s_off[NSAMP];
  __shared__ float4 s_w[NSAMP];

  const int r = blockIdx.x;
  const int c = threadIdx.x;  // channel, 0..255

  const float* roi = rois + (size_t)r * 6;
  const int   b     = (int)roi[0];
  const float theta = roi[5];

  // ---- phase 1: per-sample geometry (one sample per thread) ----
  if (c < NSAMP) {
    const float cx = roi[1] * 0.25f;
    const float cy = roi[2] * 0.25f;
    const float rw = fmaxf(roi[3] * 0.25f, 1.0f);
    const float rh = fmaxf(roi[4] * 0.25f, 1.0f);
    const float bin_w = rw * (1.0f / OUTS);
    const float bin_h = rh * (1.0f / OUTS);
    const float ct = cosf(theta), st = sinf(theta);
    const float hbw = 0.5f * bin_w, hbh = 0.5f * bin_h;
    const float xoff = 0.25f * bin_w - 0.5f * rw;
    const float yoff = 0.25f * bin_h - 0.5f * rh;

    const int py = c / (2 * OUTS);
    const int px = c - py * (2 * OUTS);
    const float yy = (float)py * hbh + yoff;
    const float xx = (float)px * hbw + xoff;
    const float x = xx * ct + yy * st + cx;
    const float y = yy * ct - xx * st + cy;

    int4   o4 = {0, 0, 0, 0};
    float4 w4 = {0.f, 0.f, 0.f, 0.f};
    if (x > -1.0f && x < (float)FW && y > -1.0f && y < (float)FH) {
      float xc = fmaxf(x, 0.f);
      float yc = fmaxf(y, 0.f);
      int x0 = (int)xc;
      int y0 = (int)yc;
      int x1, y1;
      float lx, ly;
      if (x0 >= FW - 1) { x0 = FW - 1; x1 = FW - 1; lx = 0.f; }
      else              { x1 = x0 + 1; lx = xc - (float)x0; }
      if (y0 >= FH - 1) { y0 = FH - 1; y1 = FH - 1; ly = 0.f; }
      else              { y1 = y0 + 1; ly = yc - (float)y0; }
      const float wx0 = 1.f - lx, wy0 = 1.f - ly;
      w4.x = wy0 * wx0; w4.y = wy0 * lx;
      w4.z = ly * wx0;  w4.w = ly * lx;
      int o00 = y0 * FW + x0, o01 = y0 * FW + x1;
      int o10 = y1 * FW + x0, o11 = y1 * FW + x1;
      if (CL) { o00 *= NCH; o01 *= NCH; o10 *= NCH; o11 *= NCH; }
      o4.x = o00; o4.y = o01; o4.z = o10; o4.w = o11;
    }
    s_off[c] = o4;
    s_w[c]   = w4;
  }
  __syncthreads();

  // ---- phase 2: gather + accumulate ----
  const float* fbb = feat + (size_t)b * (NCH * FH * FW);  // uniform base
  const int cbase = CL ? c : c * (FH * FW);

  float acc[OUTS * OUTS];
#pragma unroll
  for (int i = 0; i < OUTS * OUTS; ++i) acc[i] = 0.f;

#pragma unroll
  for (int py = 0; py < 2 * OUTS; ++py) {
#pragma unroll
    for (int px = 0; px < 2 * OUTS; ++px) {
      const int s = py * (2 * OUTS) + px;
      const int bin = (py >> 1) * OUTS + (px >> 1);
      const int4   o = s_off[s];   // broadcast ds_read_b128
      const float4 w = s_w[s];     // broadcast ds_read_b128
      acc[bin] += w.x * fbb[o.x + cbase] + w.y * fbb[o.y + cbase]
                + w.z * fbb[o.z + cbase] + w.w * fbb[o.w + cbase];
    }
  }

#pragma unroll
  for (int i = 0; i < OUTS * OUTS; ++i) acc[i] *= 0.25f;

  // ---- orientation circular mix (groups of 8 channels, within a wave) ----
  const float indf = (theta * 8.0f) / 6.2831853071795862f;
  const float ind0 = floorf(indf);
  const float l    = indf - ind0;
  const int   ind  = ((int)ind0) % NORI;  // ind0 >= 0
  const int   o    = c & 7;
  const int   lane = c & 63;
  const int srcLane  = (lane & 56) | ((o - ind + 8) & 7);
  const int srcLane2 = (lane & 56) | ((o - ind + 9) & 7);

  float* op = out + ((size_t)r * NCH + c) * (OUTS * OUTS);
#pragma unroll
  for (int i = 0; i < OUTS * OUTS; ++i) {
    const float v  = acc[i];
    const float vs = __shfl(v, srcLane, 64);
    const float vp = __shfl(v, srcLane2, 64);
    op[i] = (1.f - l) * vs + l * vp;
  }
}

extern "C" void kernel_launch(void* const* d_in, const int* in_sizes, int n_in,
                              void* d_out, int out_size, void* d_ws, size_t ws_size,
                              hipStream_t stream) {
  const float* feat = (const float*)d_in[0];
  const float* rois = (const float*)d_in[1];
  float* out = (float*)d_out;
  const int R = in_sizes[1] / 6;
  const int N = in_sizes[0] / (NCH * FH * FW);

  const size_t need = (size_t)N * FH * FW * NCH * sizeof(float);
  if (ws_size >= need) {
    float* ft = (float*)d_ws;
    dim3 g(FH * FW / 64, NCH / 64, N);
    transpose_nchw_nhwc<<<g, 256, 0, stream>>>(feat, ft);
    riroi_kernel<true><<<R, 256, 0, stream>>>(ft, rois, out);
  } else {
    riroi_kernel<false><<<R, 256, 0, stream>>>(feat, rois, out);
  }
}

// Round 3
// 176.672 us; speedup vs baseline: 2.6817x; 1.8924x over previous
//
#include <hip/hip_runtime.h>

typedef _Float16 half_t;

#define OUTS 7
#define NORI 8
#define NCH  256
#define FH   128
#define FW   128
#define NSAMP (2 * OUTS * 2 * OUTS)  // 196
#define NBIN  (OUTS * OUTS)          // 49

// ---------------- transpose [N,C,H,W] f32 -> [N,H,W,C] f16 ----------------
__global__ __launch_bounds__(256) void transpose_nchw_nhwc_h(
    const float* __restrict__ in, half_t* __restrict__ out) {
  __shared__ float tile[64][65];
  const int HW = FH * FW;
  const int b  = blockIdx.z;
  const int p0 = blockIdx.x * 64;   // spatial tile base
  const int c0 = blockIdx.y * 64;   // channel tile base
  const int tx = threadIdx.x & 63;
  const int ty = threadIdx.x >> 6;  // 0..3

  const float* src = in + ((size_t)b * NCH + c0) * HW + p0;
#pragma unroll
  for (int i = 0; i < 16; ++i) {
    int c = ty + i * 4;
    tile[c][tx] = src[(size_t)c * HW + tx];   // coalesced along spatial
  }
  __syncthreads();
  half_t* dst = out + ((size_t)b * HW + p0) * NCH + c0;
#pragma unroll
  for (int i = 0; i < 16; ++i) {
    int p = ty + i * 4;
    dst[(size_t)p * NCH + tx] = (half_t)tile[tx][p];  // coalesced along channel
  }
}

// ---------------- main kernel: channels-last fp16 features ----------------
__global__ __launch_bounds__(256) void riroi_cl_h(
    const half_t* __restrict__ feat, const float* __restrict__ rois,
    float* __restrict__ out) {
  __shared__ int4   s_off[NSAMP];
  __shared__ float4 s_w[NSAMP];
  __shared__ alignas(16) float s_tr[64 * NBIN];  // 12.25 KB store-transpose buf

  const int r = blockIdx.x;
  const int c = threadIdx.x;  // channel, 0..255

  const float* roi = rois + (size_t)r * 6;
  const int   b     = (int)roi[0];
  const float theta = roi[5];

  // ---- phase 1: per-sample geometry (one sample per thread) ----
  if (c < NSAMP) {
    const float cx = roi[1] * 0.25f;
    const float cy = roi[2] * 0.25f;
    const float rw = fmaxf(roi[3] * 0.25f, 1.0f);
    const float rh = fmaxf(roi[4] * 0.25f, 1.0f);
    const float bin_w = rw * (1.0f / OUTS);
    const float bin_h = rh * (1.0f / OUTS);
    const float ct = cosf(theta), st = sinf(theta);
    const float hbw = 0.5f * bin_w, hbh = 0.5f * bin_h;
    const float xoff = 0.25f * bin_w - 0.5f * rw;
    const float yoff = 0.25f * bin_h - 0.5f * rh;

    const int py = c / (2 * OUTS);
    const int px = c - py * (2 * OUTS);
    const float yy = (float)py * hbh + yoff;
    const float xx = (float)px * hbw + xoff;
    const float x = xx * ct + yy * st + cx;
    const float y = yy * ct - xx * st + cy;

    int4   o4 = {0, 0, 0, 0};
    float4 w4 = {0.f, 0.f, 0.f, 0.f};
    if (x > -1.0f && x < (float)FW && y > -1.0f && y < (float)FH) {
      float xc = fmaxf(x, 0.f);
      float yc = fmaxf(y, 0.f);
      int x0 = (int)xc;
      int y0 = (int)yc;
      int x1, y1;
      float lx, ly;
      if (x0 >= FW - 1) { x0 = FW - 1; x1 = FW - 1; lx = 0.f; }
      else              { x1 = x0 + 1; lx = xc - (float)x0; }
      if (y0 >= FH - 1) { y0 = FH - 1; y1 = FH - 1; ly = 0.f; }
      else              { y1 = y0 + 1; ly = yc - (float)y0; }
      const float wx0 = 1.f - lx, wy0 = 1.f - ly;
      w4.x = wy0 * wx0; w4.y = wy0 * lx;
      w4.z = ly * wx0;  w4.w = ly * lx;
      o4.x = (y0 * FW + x0) * NCH; o4.y = (y0 * FW + x1) * NCH;
      o4.z = (y1 * FW + x0) * NCH; o4.w = (y1 * FW + x1) * NCH;
    }
    s_off[c] = o4;
    s_w[c]   = w4;
  }
  __syncthreads();

  // ---- phase 2: gather + accumulate ----
  const half_t* fbb = feat + (size_t)b * (NCH * FH * FW) + c;  // per-lane base

  float acc[NBIN];
#pragma unroll
  for (int i = 0; i < NBIN; ++i) acc[i] = 0.f;

#pragma unroll
  for (int py = 0; py < 2 * OUTS; ++py) {
#pragma unroll
    for (int px = 0; px < 2 * OUTS; ++px) {
      const int s = py * (2 * OUTS) + px;
      const int bin = (py >> 1) * OUTS + (px >> 1);
      const int4   o = s_off[s];   // broadcast ds_read_b128
      const float4 w = s_w[s];     // broadcast ds_read_b128
      acc[bin] += w.x * (float)fbb[o.x] + w.y * (float)fbb[o.y]
                + w.z * (float)fbb[o.z] + w.w * (float)fbb[o.w];
    }
  }

#pragma unroll
  for (int i = 0; i < NBIN; ++i) acc[i] *= 0.25f;

  // ---- orientation circular mix (groups of 8 channels, within a wave) ----
  const float indf = (theta * 8.0f) / 6.2831853071795862f;
  const float ind0 = floorf(indf);
  const float l    = indf - ind0;
  const int   ind  = ((int)ind0) % NORI;  // ind0 >= 0
  const int   o    = c & 7;
  const int   lane = c & 63;
  const int srcLane  = (lane & 56) | ((o - ind + 8) & 7);
  const int srcLane2 = (lane & 56) | ((o - ind + 9) & 7);

#pragma unroll
  for (int i = 0; i < NBIN; ++i) {
    const float v  = acc[i];
    const float vs = __shfl(v, srcLane, 64);
    const float vp = __shfl(v, srcLane2, 64);
    acc[i] = (1.f - l) * vs + l * vp;   // shuffle reads complete before overwrite
  }

  // ---- coalesced store via LDS transpose, 64 channels at a time ----
  const int grp = c >> 6;
#pragma unroll
  for (int g = 0; g < 4; ++g) {
    if (grp == g) {
#pragma unroll
      for (int i = 0; i < NBIN; ++i) s_tr[(c & 63) * NBIN + i] = acc[i];
    }
    __syncthreads();
    const float4* s4 = (const float4*)s_tr;
    float4* d4 = (float4*)(out + ((size_t)r * NCH + g * 64) * NBIN);
#pragma unroll
    for (int i = 0; i < 4; ++i) {
      int idx = c + i * 256;
      if (idx < 64 * NBIN / 4) d4[idx] = s4[idx];
    }
    __syncthreads();
  }
}

// ---------------- fallback: fp32 NCHW direct ----------------
__global__ __launch_bounds__(256) void riroi_cf(
    const float* __restrict__ feat, const float* __restrict__ rois,
    float* __restrict__ out) {
  const int r = blockIdx.x;
  const int c = threadIdx.x;
  const float* roi = rois + (size_t)r * 6;
  const int   b     = (int)roi[0];
  const float cx    = roi[1] * 0.25f;
  const float cy    = roi[2] * 0.25f;
  const float rw    = fmaxf(roi[3] * 0.25f, 1.0f);
  const float rh    = fmaxf(roi[4] * 0.25f, 1.0f);
  const float theta = roi[5];
  const float bin_w = rw * (1.0f / OUTS), bin_h = rh * (1.0f / OUTS);
  const float ct = cosf(theta), st = sinf(theta);
  const float hbw = 0.5f * bin_w, hbh = 0.5f * bin_h;
  const float xoff = 0.25f * bin_w - 0.5f * rw;
  const float yoff = 0.25f * bin_h - 0.5f * rh;
  const float* fb = feat + ((size_t)b * NCH + c) * (FH * FW);
  float acc[NBIN];
#pragma unroll
  for (int i = 0; i < NBIN; ++i) acc[i] = 0.f;
  for (int py = 0; py < 2 * OUTS; ++py) {
    const float yy = (float)py * hbh + yoff;
    for (int px = 0; px < 2 * OUTS; ++px) {
      const float xx = (float)px * hbw + xoff;
      const float x = xx * ct + yy * st + cx;
      const float y = yy * ct - xx * st + cy;
      if (x > -1.0f && x < (float)FW && y > -1.0f && y < (float)FH) {
        float xc = fmaxf(x, 0.f), yc = fmaxf(y, 0.f);
        int x0 = (int)xc, y0 = (int)yc, x1, y1;
        float lx, ly;
        if (x0 >= FW - 1) { x0 = FW - 1; x1 = FW - 1; lx = 0.f; }
        else              { x1 = x0 + 1; lx = xc - (float)x0; }
        if (y0 >= FH - 1) { y0 = FH - 1; y1 = FH - 1; ly = 0.f; }
        else              { y1 = y0 + 1; ly = yc - (float)y0; }
        const float wx0 = 1.f - lx, wy0 = 1.f - ly;
        acc[(py >> 1) * OUTS + (px >> 1)] +=
            (wy0 * wx0) * fb[y0 * FW + x0] + (wy0 * lx) * fb[y0 * FW + x1]
          + (ly * wx0) * fb[y1 * FW + x0] + (ly * lx) * fb[y1 * FW + x1];
      }
    }
  }
#pragma unroll
  for (int i = 0; i < NBIN; ++i) acc[i] *= 0.25f;
  const float indf = (theta * 8.0f) / 6.2831853071795862f;
  const float ind0 = floorf(indf);
  const float l    = indf - ind0;
  const int   ind  = ((int)ind0) % NORI;
  const int   o    = c & 7;
  const int   lane = c & 63;
  const int srcLane  = (lane & 56) | ((o - ind + 8) & 7);
  const int srcLane2 = (lane & 56) | ((o - ind + 9) & 7);
  float* op = out + ((size_t)r * NCH + c) * NBIN;
#pragma unroll
  for (int i = 0; i < NBIN; ++i) {
    const float v  = acc[i];
    const float vs = __shfl(v, srcLane, 64);
    const float vp = __shfl(v, srcLane2, 64);
    op[i] = (1.f - l) * vs + l * vp;
  }
}

extern "C" void kernel_launch(void* const* d_in, const int* in_sizes, int n_in,
                              void* d_out, int out_size, void* d_ws, size_t ws_size,
                              hipStream_t stream) {
  const float* feat = (const float*)d_in[0];
  const float* rois = (const float*)d_in[1];
  float* out = (float*)d_out;
  const int R = in_sizes[1] / 6;
  const int N = in_sizes[0] / (NCH * FH * FW);

  const size_t need = (size_t)N * FH * FW * NCH * sizeof(half_t);
  if (ws_size >= need) {
    half_t* ft = (half_t*)d_ws;
    dim3 g(FH * FW / 64, NCH / 64, N);
    transpose_nchw_nhwc_h<<<g, 256, 0, stream>>>(feat, ft);
    riroi_cl_h<<<R, 256, 0, stream>>>(ft, rois, out);
  } else {
    riroi_cf<<<R, 256, 0, stream>>>(feat, rois, out);
  }
}